// Round 8
// baseline (156.866 us; speedup 1.0000x reference)
//
#include <hip/hip_runtime.h>
#include <stdint.h>

#define HW_  16384
#define CH   256
#define NB   8
#define NT   128          // n-tiles per batch (HW_/128)
#define EPSV 1e-5f

typedef float f32x4 __attribute__((ext_vector_type(4)));
typedef short s16x8 __attribute__((ext_vector_type(8)));

__device__ __forceinline__ unsigned short f2bf(float f) {
    union { float f; uint32_t u; } v; v.f = f;
    uint32_t r = (v.u + 0x7FFFu + ((v.u >> 16) & 1u)) >> 16;  // RNE
    return (unsigned short)r;
}

// async global -> LDS, 16B per lane (dest = wave-uniform base + lane*16B)
__device__ __forceinline__ void glds16(const unsigned short* g, unsigned short* l) {
    __builtin_amdgcn_global_load_lds(
        (const __attribute__((address_space(1))) uint32_t*)g,
        (__attribute__((address_space(3))) uint32_t*)l,
        16, 0, 0);
}

// ---------------------------------------------------------------------------
// K0: fused transpose + stats. Block = (ntile bx, batch b), 256 thr.
// Reads x[b][0..256][n0..n0+128] (coalesced), emits:
//  - per-(b,c) partial sum/sumsq over this n-tile (shfl-reduced, no atomics)
//  - xT tile in gemm LDS format: entry (g,n) = 8 bf16 {c=8g..8g+7} of column n
// ---------------------------------------------------------------------------
__global__ __launch_bounds__(256) void tstat_kernel(const float* __restrict__ x,
                                                    unsigned short* __restrict__ xT,
                                                    float* __restrict__ partS,
                                                    float* __restrict__ partQ) {
    const int b  = blockIdx.y;
    const int bx = blockIdx.x;
    const int n0 = bx * 128;
    const int t  = threadIdx.x;

    __shared__ uint32_t T2[128 * 132];   // [cp][n + 4 pad] u32; u32 = bf16(c=2cp)|bf16(2cp+1)<<16

    const float* xb = x + (size_t)b * CH * HW_ + n0;

    // phase 1: read 256 c-rows x 128 n, pack pairs into LDS, accumulate stats
#pragma unroll 4
    for (int it = 0; it < 16; ++it) {
        const int cp = it * 8 + (t >> 5);   // c-pair 0..127
        const int n4 = (t & 31) * 4;        // n within tile
        const float* pa = xb + (size_t)(2 * cp) * HW_ + n4;
        f32x4 va = *reinterpret_cast<const f32x4*>(pa);
        f32x4 vb = *reinterpret_cast<const f32x4*>(pa + HW_);

        float sA = va[0] + va[1] + va[2] + va[3];
        float qA = va[0]*va[0] + va[1]*va[1] + va[2]*va[2] + va[3]*va[3];
        float sB = vb[0] + vb[1] + vb[2] + vb[3];
        float qB = vb[0]*vb[0] + vb[1]*vb[1] + vb[2]*vb[2] + vb[3]*vb[3];
#pragma unroll
        for (int off = 1; off < 32; off <<= 1) {
            sA += __shfl_xor(sA, off, 32);
            qA += __shfl_xor(qA, off, 32);
            sB += __shfl_xor(sB, off, 32);
            qB += __shfl_xor(qB, off, 32);
        }
        if ((t & 31) == 0) {
            partS[(size_t)(b * CH + 2 * cp    ) * NT + bx] = sA;
            partQ[(size_t)(b * CH + 2 * cp    ) * NT + bx] = qA;
            partS[(size_t)(b * CH + 2 * cp + 1) * NT + bx] = sB;
            partQ[(size_t)(b * CH + 2 * cp + 1) * NT + bx] = qB;
        }

        uint4 pk;
        pk.x = (uint32_t)f2bf(va[0]) | ((uint32_t)f2bf(vb[0]) << 16);
        pk.y = (uint32_t)f2bf(va[1]) | ((uint32_t)f2bf(vb[1]) << 16);
        pk.z = (uint32_t)f2bf(va[2]) | ((uint32_t)f2bf(vb[2]) << 16);
        pk.w = (uint32_t)f2bf(va[3]) | ((uint32_t)f2bf(vb[3]) << 16);
        *reinterpret_cast<uint4*>(&T2[cp * 132 + n4]) = pk;   // b128, conflict-free
    }
    __syncthreads();

    // phase 2: emit xT tile. entry idx = g*128 + n  ->  16B = c octet of column n
    uint4* dst = reinterpret_cast<uint4*>(xT + ((size_t)(b * NT + bx)) * (128 * CH));
#pragma unroll 4
    for (int it = 0; it < 16; ++it) {
        const int idx = it * 256 + t;    // 0..4095
        const int g   = idx >> 7;        // 0..31
        const int n   = idx & 127;
        uint4 o;
        o.x = T2[(g * 4 + 0) * 132 + n];  // column reads: bank = n mod 32 -> free
        o.y = T2[(g * 4 + 1) * 132 + n];
        o.z = T2[(g * 4 + 2) * 132 + n];
        o.w = T2[(g * 4 + 3) * 132 + n];
        dst[idx] = o;                     // consecutive 16B -> fully coalesced
    }
}

// ---------------------------------------------------------------------------
// K2: reduce partials, finalize stats, fold into A' (bf16 [b][o][c]) + D'.
// ---------------------------------------------------------------------------
__global__ __launch_bounds__(256) void prep_kernel(const float* __restrict__ partS,
                                                   const float* __restrict__ partQ,
                                                   const float* __restrict__ params,
                                                   const float* __restrict__ W,
                                                   unsigned short* __restrict__ Ap,
                                                   float* __restrict__ Dp) {
    const int b   = blockIdx.x;
    const int tid = threadIdx.x;
    __shared__ float mu[CH], ri[CH], rs[CH], rq[CH];

    // reduce 128 partials for c = tid
    float s = 0.f, q = 0.f;
    const f32x4* ps = reinterpret_cast<const f32x4*>(partS + (size_t)(b * CH + tid) * NT);
    const f32x4* pq = reinterpret_cast<const f32x4*>(partQ + (size_t)(b * CH + tid) * NT);
#pragma unroll 8
    for (int i = 0; i < NT / 4; ++i) {
        f32x4 a = ps[i], c4 = pq[i];
        s += a[0] + a[1] + a[2] + a[3];
        q += c4[0] + c4[1] + c4[2] + c4[3];
    }

    float m = s * (1.0f / HW_);
    float v = q * (1.0f / HW_) - m * m;
    mu[tid] = m;
    ri[tid] = rsqrtf(v + EPSV);
    rs[tid] = s; rq[tid] = q;
    __syncthreads();
    for (int off = 128; off > 0; off >>= 1) {
        if (tid < off) { rs[tid] += rs[tid + off]; rq[tid] += rq[tid + off]; }
        __syncthreads();
    }
    const float invN = 1.0f / ((float)CH * (float)HW_);
    const float mln  = rs[0] * invN;
    const float vln  = rq[0] * invN - mln * mln;
    const float rln  = rsqrtf(vln + EPSV);

    const int o = tid;
    const float gamma = params[b * 2 * CH + o];
    const float beta  = params[b * 2 * CH + CH + o];
    const float4* w1p = reinterpret_cast<const float4*>(W + (size_t)o * 2 * CH);
    const float4* w2p = reinterpret_cast<const float4*>(W + (size_t)o * 2 * CH + CH);
    unsigned short* aprow = Ap + ((size_t)(b * CH + o)) * CH;
    float t1 = 0.f, t2 = 0.f;
    for (int c4i = 0; c4i < CH / 4; ++c4i) {
        float4 w1 = w1p[c4i];
        float4 w2 = w2p[c4i];
        float w1a[4] = {w1.x, w1.y, w1.z, w1.w};
        float w2a[4] = {w2.x, w2.y, w2.z, w2.w};
        const int c = c4i * 4;
        ushort4 pk;
        unsigned short* pka = (unsigned short*)&pk;
#pragma unroll
        for (int j = 0; j < 4; ++j) {
            float ric = ri[c + j];
            float a   = gamma * (w1a[j] * ric + w2a[j] * rln);
            pka[j] = f2bf(a);
            t1 += w1a[j] * ric * mu[c + j];
            t2 += w2a[j];
        }
        *reinterpret_cast<ushort4*>(aprow + c) = pk;
    }
    const float d = -(t1 + rln * mln * t2);
    Dp[b * CH + o] = gamma * d + beta;
}

// ---------------------------------------------------------------------------
// K3: batched MFMA GEMM, pure-DMA staging.
// out[b][m][n] = sum_c A'[b][m][c] * x[b][c][n] + D'
// BM=256, BN=128, BK=32. 512 thr = 8 waves, wave 64x64 (4x4 frags 16x16x32).
// K-loop: barrier -> DMA As(kb+1) [2/wave] + Xs(kb+1) [1/wave] -> compute(kb).
// Both LDS tiles DMA'd linearly (As from A', Xs from xT) -> no in-loop VALU,
// no ds_writes, ~105 live VGPRs: no spill at (512,4), real 2 blocks/CU.
// ---------------------------------------------------------------------------
__global__ __launch_bounds__(512, 4) void gemm_kernel(const unsigned short* __restrict__ xT,
                                                      const unsigned short* __restrict__ Ap,
                                                      const float* __restrict__ Dp,
                                                      float* __restrict__ out) {
    __shared__ unsigned short As[2][4 * 256 * 8];  // [buf][g][m][8]  16 KB each
    __shared__ unsigned short Xs[2][4 * 128 * 8];  // [buf][g][n][8]   8 KB each

    const int b   = blockIdx.y;
    const int bx  = blockIdx.x;
    const int n0  = bx * 128;
    const int t   = threadIdx.x;
    const int w   = t >> 6;
    const int l   = t & 63;
    const int wm  = w >> 1;        // 0..3
    const int wn  = w & 1;         // 0..1
    const int lhi = l >> 4;        // 0..3 (k-group)
    const int llo = l & 15;        // row/col within fragment

    // acc init = bias D' (MFMA C-operand): D row = wm*64+fm*16+lhi*4+r
    f32x4 acc[4][4];
    const float* dpb = Dp + b * CH;
#pragma unroll
    for (int fm = 0; fm < 4; ++fm) {
        f32x4 d = *reinterpret_cast<const f32x4*>(dpb + wm * 64 + fm * 16 + lhi * 4);
#pragma unroll
        for (int fn = 0; fn < 4; ++fn) acc[fm][fn] = d;
    }

    const unsigned short* apb = Ap + (size_t)b * CH * CH;
    const unsigned short* xtb = xT + ((size_t)(b * NT + bx)) * (128 * CH);

    // As DMA mapping: wave w issues i=2w,2w+1 -> (g=i&3, q=i>>2); lane=m row
    const int i0 = 2 * w,      i1 = 2 * w + 1;
    const int g0 = i0 & 3,     q0 = i0 >> 2;
    const int g1 = i1 & 3,     q1 = i1 >> 2;
    const unsigned short* aglob0 = apb + (size_t)(q0 * 64 + l) * CH + g0 * 8;
    const unsigned short* aglob1 = apb + (size_t)(q1 * 64 + l) * CH + g1 * 8;
    unsigned short* alds0 = &As[0][g0 * 2048 + q0 * 512];  // + l*16B by HW
    unsigned short* alds1 = &As[0][g1 * 2048 + q1 * 512];

    // Xs DMA mapping: wave w -> (g_l = w>>1, n_half = w&1); lane = n
    const int gl = w >> 1, nh = w & 1;
    const unsigned short* xglob = xtb + (size_t)((gl * 128) + nh * 64 + l) * 8;
    unsigned short* xlds = &Xs[0][(gl * 128 + nh * 64) * 8];

    // prologue: DMA tile 0
    glds16(aglob0, alds0);
    glds16(aglob1, alds1);
    glds16(xglob,  xlds);

#pragma unroll
    for (int kb = 0; kb < 8; ++kb) {
        __syncthreads();   // vmcnt(0) drain: DMA(kb) landed; compute(kb-1) done
        const int cur = kb & 1, nxt = cur ^ 1;

        if (kb < 7) {      // DMA(kb+1) in flight through compute(kb)
            glds16(aglob0 + (kb + 1) * 32,   alds0 + nxt * 8192);
            glds16(aglob1 + (kb + 1) * 32,   alds1 + nxt * 8192);
            glds16(xglob  + (kb + 1) * 4096, xlds  + nxt * 4096);
        }

        // compute(kb)
        s16x8 af[4];
#pragma unroll
        for (int fm = 0; fm < 4; ++fm)
            af[fm] = *reinterpret_cast<const s16x8*>(&As[cur][lhi * 2048 + (wm * 64 + fm * 16 + llo) * 8]);
#pragma unroll
        for (int fn = 0; fn < 4; ++fn) {
            const int nr = wn * 64 + fn * 16 + llo;
            s16x8 bfr = *reinterpret_cast<const s16x8*>(&Xs[cur][lhi * 1024 + nr * 8]);
#pragma unroll
            for (int fm = 0; fm < 4; ++fm)
                acc[fm][fn] = __builtin_amdgcn_mfma_f32_16x16x32_bf16(af[fm], bfr, acc[fm][fn], 0, 0, 0);
        }
    }

    // epilogue: bias already folded into acc
#pragma unroll
    for (int fm = 0; fm < 4; ++fm) {
        const int m = wm * 64 + fm * 16 + lhi * 4;
        float* obase = out + (size_t)(b * CH + m) * HW_ + n0 + wn * 64 + llo;
#pragma unroll
        for (int fn = 0; fn < 4; ++fn) {
#pragma unroll
            for (int r = 0; r < 4; ++r)
                obase[(size_t)r * HW_ + fn * 16] = acc[fm][fn][r];
        }
    }
}

// ---------------------------------------------------------------------------
extern "C" void kernel_launch(void* const* d_in, const int* in_sizes, int n_in,
                              void* d_out, int out_size, void* d_ws, size_t ws_size,
                              hipStream_t stream) {
    const float* x      = (const float*)d_in[0];
    const float* params = (const float*)d_in[1];
    const float* W      = (const float*)d_in[2];
    float* out = (float*)d_out;
    char*  ws  = (char*)d_ws;

    float*          partS = (float*)(ws + 0);                  // 1 MB
    float*          partQ = (float*)(ws + (1u << 20));         // 1 MB
    float*          Dp    = (float*)(ws + (2u << 20));         // 8 KB
    unsigned short* Ap    = (unsigned short*)(ws + (3u << 20)); // 1 MB
    unsigned short* xT    = (unsigned short*)(ws + (4u << 20)); // 64 MB

    hipLaunchKernelGGL(tstat_kernel, dim3(NT, NB), dim3(256), 0, stream, x, xT, partS, partQ);
    hipLaunchKernelGGL(prep_kernel,  dim3(NB),     dim3(256), 0, stream, partS, partQ, params, W, Ap, Dp);
    hipLaunchKernelGGL(gemm_kernel,  dim3(NT, NB), dim3(512), 0, stream, xT, Ap, Dp, out);
}

// Round 10
// 96.749 us; speedup vs baseline: 1.6214x; 1.6214x over previous
//
#include <hip/hip_runtime.h>
#include <stdint.h>

#define HW_  16384
#define CH   256
#define NB   8
#define EPSV 1e-5f

typedef float f32x4 __attribute__((ext_vector_type(4)));
typedef short s16x8 __attribute__((ext_vector_type(8)));

__device__ __forceinline__ unsigned short f2bf(float f) {
    union { float f; uint32_t u; } v; v.f = f;
    uint32_t r = (v.u + 0x7FFFu + ((v.u >> 16) & 1u)) >> 16;  // RNE
    return (unsigned short)r;
}

// async global -> LDS. Global source address is PER-LANE; LDS dest is
// wave-uniform base + lane*16B (HW-appended).  [m104/m108]
__device__ __forceinline__ void glds16(const unsigned short* g, unsigned short* l) {
    __builtin_amdgcn_global_load_lds(
        (const __attribute__((address_space(1))) uint32_t*)g,
        (__attribute__((address_space(3))) uint32_t*)l,
        16, 0, 0);
}

// ---------------------------------------------------------------------------
// K1: per-(b,c) sum and sum-of-squares over H*W. 2048 blocks x 256 thr.
// ---------------------------------------------------------------------------
__global__ __launch_bounds__(256) void stats_kernel(const float* __restrict__ x,
                                                    float* __restrict__ sums,
                                                    float* __restrict__ sumsq) {
    const int bc  = blockIdx.x;
    const int tid = threadIdx.x;
    const float4* p = reinterpret_cast<const float4*>(x + (size_t)bc * HW_);
    float s = 0.f, q = 0.f;
#pragma unroll 4
    for (int i = tid; i < HW_ / 4; i += 256) {
        float4 v = p[i];
        s += v.x + v.y + v.z + v.w;
        q += v.x * v.x + v.y * v.y + v.z * v.z + v.w * v.w;
    }
    __shared__ float rs[256], rq[256];
    rs[tid] = s; rq[tid] = q;
    __syncthreads();
    for (int off = 128; off > 0; off >>= 1) {
        if (tid < off) { rs[tid] += rs[tid + off]; rq[tid] += rq[tid + off]; }
        __syncthreads();
    }
    if (tid == 0) { sums[bc] = rs[0]; sumsq[bc] = rq[0]; }
}

// ---------------------------------------------------------------------------
// K2: finalize stats, fold into A' + D'. A' written PRE-TILED in the gemm's
// LDS order: Atile[b][kb][g][m][8]  (kb = K-tile, g = k-octet, m = o).
// ---------------------------------------------------------------------------
__global__ __launch_bounds__(256) void prep_kernel(const float* __restrict__ sums,
                                                   const float* __restrict__ sumsq,
                                                   const float* __restrict__ params,
                                                   const float* __restrict__ W,
                                                   unsigned short* __restrict__ Atile,
                                                   float* __restrict__ Dp) {
    const int b   = blockIdx.x;
    const int tid = threadIdx.x;
    __shared__ float mu[CH], ri[CH], rs[CH], rq[CH];
    float s = sums[b * CH + tid];
    float q = sumsq[b * CH + tid];
    float m = s * (1.0f / HW_);
    float v = q * (1.0f / HW_) - m * m;
    mu[tid] = m;
    ri[tid] = rsqrtf(v + EPSV);
    rs[tid] = s; rq[tid] = q;
    __syncthreads();
    for (int off = 128; off > 0; off >>= 1) {
        if (tid < off) { rs[tid] += rs[tid + off]; rq[tid] += rq[tid + off]; }
        __syncthreads();
    }
    const float invN = 1.0f / ((float)CH * (float)HW_);
    const float mln  = rs[0] * invN;
    const float vln  = rq[0] * invN - mln * mln;
    const float rln  = rsqrtf(vln + EPSV);

    const int o = tid;
    const float gamma = params[b * 2 * CH + o];
    const float beta  = params[b * 2 * CH + CH + o];
    const float4* w1p = reinterpret_cast<const float4*>(W + (size_t)o * 2 * CH);
    const float4* w2p = reinterpret_cast<const float4*>(W + (size_t)o * 2 * CH + CH);
    unsigned short* ab = Atile + (size_t)b * (8 * 4 * 256 * 8);  // 65536 shorts/batch
    float t1 = 0.f, t2 = 0.f;
    for (int c4 = 0; c4 < CH / 4; ++c4) {
        float4 w1 = w1p[c4];
        float4 w2 = w2p[c4];
        float w1a[4] = {w1.x, w1.y, w1.z, w1.w};
        float w2a[4] = {w2.x, w2.y, w2.z, w2.w};
        const int c = c4 * 4;
        ushort4 pk;
        unsigned short* pka = (unsigned short*)&pk;
#pragma unroll
        for (int j = 0; j < 4; ++j) {
            float ric = ri[c + j];
            float a   = gamma * (w1a[j] * ric + w2a[j] * rln);
            pka[j] = f2bf(a);
            t1 += w1a[j] * ric * mu[c + j];
            t2 += w2a[j];
        }
        // tile coords for this c-quad: kb = c>>5, g = (c>>3)&3, e0 = c&4
        const int kb = c >> 5, g = (c >> 3) & 3, e0 = c & 4;
        *reinterpret_cast<ushort4*>(&ab[(size_t)(((kb * 4 + g) * 256 + o) * 8 + e0)]) = pk;
    }
    const float d = -(t1 + rln * mln * t2);
    Dp[b * CH + o] = gamma * d + beta;
}

// ---------------------------------------------------------------------------
// K3: batched MFMA GEMM (R7 schedule; A-DMA coalesced from pre-tiled Atile).
// out[b][m][n] = sum_c A'[b][m][c] * x[b][c][n] + D'
// BM=256, BN=128, BK=32. 512 thr = 8 waves, wave 64x64 (4x4 frags 16x16x32).
// Per K-step: [vmcnt(2) lgkmcnt(0); barrier] -> DMA As(kb+1) (lane-consecutive
// 16B, 1KB/instr) -> load x(kb+2) -> compute(kb) -> ds_write Xs(kb+1).
// ---------------------------------------------------------------------------
__global__ __launch_bounds__(512, 4) void gemm_kernel(const float* __restrict__ x,
                                                      const unsigned short* __restrict__ Atile,
                                                      const float* __restrict__ Dp,
                                                      float* __restrict__ out) {
    __shared__ unsigned short As[2][4 * 256 * 8];  // [buf][g][m][8]   16 KB each
    __shared__ unsigned short Xs[2][4 * 128 * 8];  // [buf][g][n_p][8]  8 KB each

    const int b   = blockIdx.y;
    const int n0  = blockIdx.x * 128;
    const int t   = threadIdx.x;
    const int w   = t >> 6;
    const int l   = t & 63;
    const int wm  = w >> 1;        // 0..3
    const int wn  = w & 1;         // 0..1
    const int lhi = l >> 4;        // 0..3 (k-group)
    const int llo = l & 15;        // row/col within fragment

    // acc init = bias D' (MFMA C-operand)
    f32x4 acc[4][4];
    const float* dpb = Dp + b * CH;
#pragma unroll
    for (int fm = 0; fm < 4; ++fm) {
        f32x4 d = *reinterpret_cast<const f32x4*>(dpb + wm * 64 + fm * 16 + lhi * 4);
#pragma unroll
        for (int fn = 0; fn < 4; ++fn) acc[fm][fn] = d;
    }

    const size_t xbase = (size_t)b * CH * HW_ + n0;
    const unsigned short* apb = Atile + (size_t)b * (8 * 4 * 256 * 8);
    uint32_t* Xs32 = reinterpret_cast<uint32_t*>(&Xs[0][0]);

    // ---- As DMA mapping: wave w issues instrs i=2w,2w+1; i -> (g=i&3, q=i>>2)
    // global: per-lane consecutive 16B within [kb][g][q*64..q*64+63][8] (BUG
    // FIX vs R9: + l on the GLOBAL side; HW only lane-offsets the LDS side).
    const int i0 = 2 * w,      i1 = 2 * w + 1;
    const int g0 = i0 & 3,     q0 = i0 >> 2;
    const int g1 = i1 & 3,     q1 = i1 >> 2;
    const unsigned short* aglob0 = apb + (size_t)(g0 * 256 + q0 * 64 + l) * 8;
    const unsigned short* aglob1 = apb + (size_t)(g1 * 256 + q1 * 64 + l) * 8;
    unsigned short* alds0 = &As[0][g0 * 2048 + q0 * 512];  // + l*16B by HW
    unsigned short* alds1 = &As[0][g1 * 2048 + q1 * 512];

    // ---- Xs staging mapping
    const int kp = t >> 5;              // k-pair 0..15 (rows 2kp, 2kp+1)
    const int nq = t & 31;              // n-quad (half-wave = 512B row segment)
    const int xg = kp >> 2;             // Xs g
    const int xh = kp & 3;              // u32 slot within octet
    const float* xlane = x + xbase + (size_t)(2 * kp) * HW_ + nq * 4;

    // read-side swizzled n per fn
    int npr[4];
#pragma unroll
    for (int fn = 0; fn < 4; ++fn) {
        const int nr = wn * 64 + fn * 16 + llo;
        npr[fn] = nr ^ ((nr >> 3) & 7);
    }

    // ---- prologue: DMA As(0), load x tiles 0 and 1, stage Xs[0]
    glds16(aglob0, alds0);
    glds16(aglob1, alds1);
    f32x4 xa[2], xb[2];
    xa[0] = *reinterpret_cast<const f32x4*>(xlane);
    xb[0] = *reinterpret_cast<const f32x4*>(xlane + HW_);
    xa[1] = *reinterpret_cast<const f32x4*>(xlane + (size_t)32 * HW_);
    xb[1] = *reinterpret_cast<const f32x4*>(xlane + (size_t)32 * HW_ + HW_);
#pragma unroll
    for (int j = 0; j < 4; ++j) {
        const int n  = nq * 4 + j;
        const int np = n ^ ((n >> 3) & 7);
        Xs32[xg * 512 + np * 4 + xh] =
            (uint32_t)f2bf(xa[0][j]) | ((uint32_t)f2bf(xb[0][j]) << 16);
    }

#pragma unroll
    for (int kb = 0; kb < 8; ++kb) {
        const int cur = kb & 1, nxt = cur ^ 1;

        // counted-vmcnt barrier: As(kb) DMA drained; newest 2 x-prefetch loads
        // may stay in flight. Last iter: nothing outstanding allowed.
        if (kb == 7) {
            asm volatile("s_waitcnt vmcnt(0) lgkmcnt(0)" ::: "memory");
        } else {
            asm volatile("s_waitcnt vmcnt(2) lgkmcnt(0)" ::: "memory");
        }
        __builtin_amdgcn_s_barrier();

        if (kb < 7) {
            // DMA As(kb+1): lane-consecutive 16B -> 1KB coalesced per instr
            glds16(aglob0 + (kb + 1) * 8192, alds0 + nxt * 8192);
            glds16(aglob1 + (kb + 1) * 8192, alds1 + nxt * 8192);
        }
        if (kb < 6) {
            const float* xp = xlane + (size_t)(kb + 2) * 32 * HW_;
            xa[cur] = *reinterpret_cast<const f32x4*>(xp);
            xb[cur] = *reinterpret_cast<const f32x4*>(xp + HW_);
        }

        // compute(kb) from cur buffers
        s16x8 af[4];
#pragma unroll
        for (int fm = 0; fm < 4; ++fm)
            af[fm] = *reinterpret_cast<const s16x8*>(&As[cur][lhi * 2048 + (wm * 64 + fm * 16 + llo) * 8]);
#pragma unroll
        for (int fn = 0; fn < 4; ++fn) {
            s16x8 bfr = *reinterpret_cast<const s16x8*>(&Xs[cur][lhi * 1024 + npr[fn] * 8]);
#pragma unroll
            for (int fm = 0; fm < 4; ++fm)
                acc[fm][fn] = __builtin_amdgcn_mfma_f32_16x16x32_bf16(af[fm], bfr, acc[fm][fn], 0, 0, 0);
        }

        // stage Xs(kb+1) AFTER compute: xa[nxt] is ~2 phases old -> no stall
        if (kb < 7) {
#pragma unroll
            for (int j = 0; j < 4; ++j) {
                const int n  = nq * 4 + j;
                const int np = n ^ ((n >> 3) & 7);
                Xs32[nxt * 2048 + xg * 512 + np * 4 + xh] =
                    (uint32_t)f2bf(xa[nxt][j]) | ((uint32_t)f2bf(xb[nxt][j]) << 16);
            }
        }
    }

    // epilogue: bias already folded into acc
#pragma unroll
    for (int fm = 0; fm < 4; ++fm) {
        const int m = wm * 64 + fm * 16 + lhi * 4;
        float* obase = out + (size_t)(b * CH + m) * HW_ + n0 + wn * 64 + llo;
#pragma unroll
        for (int fn = 0; fn < 4; ++fn) {
#pragma unroll
            for (int r = 0; r < 4; ++r)
                obase[(size_t)r * HW_ + fn * 16] = acc[fm][fn][r];
        }
    }
}

// ---------------------------------------------------------------------------
extern "C" void kernel_launch(void* const* d_in, const int* in_sizes, int n_in,
                              void* d_out, int out_size, void* d_ws, size_t ws_size,
                              hipStream_t stream) {
    const float* x      = (const float*)d_in[0];
    const float* params = (const float*)d_in[1];
    const float* W      = (const float*)d_in[2];
    float* out = (float*)d_out;
    float* ws  = (float*)d_ws;

    float* sums  = ws;                 // 2048 f32
    float* sumsq = ws + 2048;          // 2048 f32
    float* Dp    = ws + 4096;          // 2048 f32
    unsigned short* Atile = (unsigned short*)(ws + 6144);  // 8*65536 shorts = 1 MB

    hipLaunchKernelGGL(stats_kernel, dim3(NB * CH), dim3(256), 0, stream, x, sums, sumsq);
    hipLaunchKernelGGL(prep_kernel,  dim3(NB),      dim3(256), 0, stream, sums, sumsq, params, W, Atile, Dp);
    hipLaunchKernelGGL(gemm_kernel,  dim3(HW_ / 128, NB), dim3(512), 0, stream, x, Atile, Dp, out);
}